// Round 5
// baseline (167.354 us; speedup 1.0000x reference)
//
#include <hip/hip_runtime.h>

// Problem constants
#define BATCH 4
#define SEQ   2048
#define INC   512
#define NH    8
#define OUTC  64      // space dim; head dim = 65
#define DD    65

typedef float f32x4 __attribute__((ext_vector_type(4)));
typedef short short8 __attribute__((ext_vector_type(8)));
typedef short short4v __attribute__((ext_vector_type(4)));
typedef unsigned int uint2v __attribute__((ext_vector_type(2)));
typedef unsigned short us;

static __device__ __forceinline__ us f2b(float f) {
  unsigned int u = __float_as_uint(f);
  u = (u + 0x7FFFu + ((u >> 16) & 1u)) >> 16;   // RNE f32->bf16
  return (us)u;
}
static __device__ __forceinline__ float b2f(us h) {
  return __uint_as_float(((unsigned int)h) << 16);
}
static __device__ __forceinline__ unsigned int pk2(float lo, float hi) {
  unsigned int r;
  asm("v_cvt_pk_bf16_f32 %0, %1, %2" : "=v"(r) : "v"(lo), "v"(hi));
  return r;
}

#define GLDS(g, l) __builtin_amdgcn_global_load_lds( \
    (const __attribute__((address_space(1))) void*)(g), \
    (__attribute__((address_space(3))) void*)(l), 16, 0, 0)

// Logits are a*cinner with cinner <= -1 (Lorentz), so 0 upper-bounds the max.
// MASKV chosen so exp2f(al2*MASKV - al2*m_) == 0 exactly for any m_ in [0,100].
#define MASKV (-60000.0f)

// ---------------------------------------------------------------------------
// Kernel 0: f32 -> bf16 conversion for X (both) and W (all three).
// ---------------------------------------------------------------------------
__global__ __launch_bounds__(256) void tobf16_kernel(
    const float* __restrict__ Xq, const float* __restrict__ Xs,
    const float* __restrict__ Wq, const float* __restrict__ Wk,
    const float* __restrict__ Wv,
    us* __restrict__ dXq, us* __restrict__ dXs,
    us* __restrict__ dWq, us* __restrict__ dWk, us* __restrict__ dWv)
{
  const int which = blockIdx.y;
  const float* src;
  us* dst;
  int n;
  switch (which) {
    case 0: src = Xq; dst = dXq; n = BATCH * SEQ * INC; break;
    case 1: src = Xs; dst = dXs; n = BATCH * SEQ * INC; break;
    case 2: src = Wq; dst = dWq; n = NH * OUTC * INC; break;
    case 3: src = Wk; dst = dWk; n = NH * OUTC * INC; break;
    default: src = Wv; dst = dWv; n = NH * OUTC * INC; break;
  }
  for (long i = (long)blockIdx.x * 256 + threadIdx.x; i * 4 < n;
       i += (long)gridDim.x * 256) {
    f32x4 v = *(const f32x4*)(src + i * 4);
    short4v o;
    o[0] = (short)f2b(v[0]); o[1] = (short)f2b(v[1]);
    o[2] = (short)f2b(v[2]); o[3] = (short)f2b(v[3]);
    *(short4v*)(dst + i * 4) = o;
  }
}

// ---------------------------------------------------------------------------
// Kernel 1: per-head projections from bf16 inputs, GLDS double-buffered.
// ---------------------------------------------------------------------------
__global__ __launch_bounds__(256) void proj_kernel(
    const us* __restrict__ Xqb, const us* __restrict__ Xsb,
    const us* __restrict__ Wqb, const us* __restrict__ Wkb, const us* __restrict__ Wvb,
    const float* __restrict__ Bq, const float* __restrict__ Bk, const float* __restrict__ Bv,
    us* __restrict__ qs, float* __restrict__ qt,
    us* __restrict__ ks, us* __restrict__ kta,
    us* __restrict__ vs, us* __restrict__ vth, us* __restrict__ vtl)
{
  const int which = blockIdx.z;
  const us* X = (which == 0) ? Xqb : Xsb;
  const us* W = (which == 0) ? Wqb : (which == 1 ? Wkb : Wvb);
  const float* Bb = (which == 0) ? Bq : (which == 1 ? Bk : Bv);
  us* outs = (which == 0) ? qs : (which == 1 ? ks : vs);

  const int m0 = blockIdx.x * 64;
  const int h  = blockIdx.y;
  const int n0 = h * 64;

  __shared__ alignas(16) us lX[2][64 * 64];
  __shared__ alignas(16) us lW[2][64 * 64];

  const int tid  = threadIdx.x;
  const int lane = tid & 63;
  const int wave = tid >> 6;
  const int arow = lane & 15;
  const int agrp = lane >> 4;
  const int rl   = lane >> 3;
  const int chx  = ((lane & 7) ^ rl) * 8;
  const int r0   = wave * 8 + rl;
  const int r1   = r0 + 32;

#define PSTAGE(buf, k0) do { \
    GLDS(X + (size_t)(m0 + r0) * INC + (k0) + chx, &lX[buf][wave * 512]); \
    GLDS(X + (size_t)(m0 + r1) * INC + (k0) + chx, &lX[buf][2048 + wave * 512]); \
    GLDS(W + (size_t)(n0 + r0) * INC + (k0) + chx, &lW[buf][wave * 512]); \
    GLDS(W + (size_t)(n0 + r1) * INC + (k0) + chx, &lW[buf][2048 + wave * 512]); \
  } while (0)

  f32x4 acc[4] = {};
  PSTAGE(0, 0);

  for (int kk = 0; kk < 8; ++kk) {
    const int cur = kk & 1;
    if (kk < 7) {
      PSTAGE(cur ^ 1, (kk + 1) * 64);
      asm volatile("s_waitcnt vmcnt(4)");
    } else {
      asm volatile("s_waitcnt vmcnt(0)");
    }
    __builtin_amdgcn_s_barrier();
#pragma unroll
    for (int kc = 0; kc < 2; ++kc) {
      short8 af = *(const short8*)&lX[cur][(wave * 16 + arow) * 64 + (((kc * 4 + agrp) ^ (arow & 7)) * 8)];
#pragma unroll
      for (int c = 0; c < 4; ++c) {
        short8 bf = *(const short8*)&lW[cur][(c * 16 + arow) * 64 + (((kc * 4 + agrp) ^ (arow & 7)) * 8)];
        acc[c] = __builtin_amdgcn_mfma_f32_16x16x32_bf16(af, bf, acc[c], 0, 0, 0);
      }
    }
    __builtin_amdgcn_s_barrier();
  }

  float bcol[4];
#pragma unroll
  for (int c = 0; c < 4; ++c) bcol[c] = Bb[n0 + c * 16 + arow];
#pragma unroll
  for (int r = 0; r < 4; ++r) {
    float s2 = 0.f;
#pragma unroll
    for (int c = 0; c < 4; ++c) {
      float v = acc[c][r] + bcol[c];
      acc[c][r] = v;
      s2 += v * v;
    }
    s2 += __shfl_xor(s2, 1); s2 += __shfl_xor(s2, 2);
    s2 += __shfl_xor(s2, 4); s2 += __shfl_xor(s2, 8);
    float tv = sqrtf(s2 + 1.0f);
    int gs = m0 + wave * 16 + agrp * 4 + r;
    int bi = gs >> 11, si = gs & (SEQ - 1);
    size_t rowbase = (size_t)(bi * NH + h) * SEQ + si;
    size_t obase = rowbase * 64;
#pragma unroll
    for (int c = 0; c < 4; ++c) outs[obase + c * 16 + arow] = f2b(acc[c][r]);
    if (arow == 0) {
      if (which == 0) {
        qt[rowbase] = tv;
      } else {
        us th = f2b(tv);
        us tl = f2b(tv - b2f(th));
        if (which == 1) {
          short8 row = {};
          row[0] = (short)(th ^ 0x8000);
          row[1] = (short)(tl ^ 0x8000);
          row[2] = (short)(th ^ 0x8000);
          *(short8*)&kta[rowbase * 8] = row;
        } else {
          vth[rowbase] = th;
          vtl[rowbase] = tl;
        }
      }
    }
  }
}

// ---------------------------------------------------------------------------
// Kernel 2: transpose V space-part per (b,h): [S,64] -> [64,S]  (bf16)
// ---------------------------------------------------------------------------
__global__ __launch_bounds__(256) void transpose_v_kernel(
    const us* __restrict__ vs, us* __restrict__ vT)
{
  const int bh = blockIdx.y;
  const int s0 = blockIdx.x * 64;
  __shared__ us lT[64 * 80];
  const int tid = threadIdx.x;
#pragma unroll
  for (int u0 = 0; u0 < 2; ++u0) {
    int u = tid + u0 * 256;
    int row = u >> 3, ch = u & 7;
    short8 v = *(const short8*)&vs[((size_t)bh * SEQ + s0 + row) * 64 + ch * 8];
    *(short8*)&lT[row * 80 + ch * 8] = v;
  }
  __syncthreads();
#pragma unroll
  for (int u0 = 0; u0 < 2; ++u0) {
    int u = tid + u0 * 256;
    int o = u >> 3, sc = u & 7;
    short8 w;
#pragma unroll
    for (int j = 0; j < 8; ++j) w[j] = lT[(sc * 8 + j) * 80 + o];
    *(short8*)&vT[((size_t)bh * 64 + o) * SEQ + s0 + sc * 8] = w;
  }
}

// ---------------------------------------------------------------------------
// Kernel 3: split-k causal flash attention (KBLK=32). 1024 blocks:
// block (pair x, half h) = {half h of qb=x} u {half h of qb=31-x} = 33 tiles.
// Writes per-q-tile partials: [64 rows][68]: 64 space, tsum, lsum, m, pad.
// m_ init = 0 (valid upper bound: logits = a*cinner <= -a < 0); mask = MASKV
// so masked P underflows to exactly 0 (fully-masked rows emit L=0,M=0).
// ---------------------------------------------------------------------------
__global__ __launch_bounds__(256) void attn_kernel(
    const us* __restrict__ qs, const float* __restrict__ qt,
    const us* __restrict__ ks, const us* __restrict__ kta,
    const us* __restrict__ vT, const us* __restrict__ vth, const us* __restrict__ vtl,
    const float* __restrict__ scale_p, float* __restrict__ part)
{
  // XCD-aware swizzle: 32 blocks of one bh land on one XCD.
  const int f = blockIdx.x;
  const int xcd = f & 7, idx = f >> 3;
  const int bh = xcd * 4 + (idx >> 5);
  const int inner = idx & 31;
  const int xb = inner >> 1;
  const int hf = inner & 1;
  const float al2 = (2.0f / scale_p[0]) * 1.44269504088896f;  // a * log2(e)

  __shared__ alignas(16) us lK[2][32 * 64];
  __shared__ alignas(16) us lV[2][64 * 32];
  __shared__ alignas(16) us lKt[2][32 * 8];
  __shared__ alignas(16) us lVt[2][64];
  __shared__ alignas(16) us lP[4][16 * 32];

  const int tid  = threadIdx.x;
  const int lane = tid & 63;
  const int wave = tid >> 6;
  const int arow = lane & 15;
  const int agrp = lane >> 4;

  const size_t bhbase = (size_t)bh * SEQ;
  const us* kgp  = ks  + bhbase * 64;
  const us* vgp  = vT  + (size_t)bh * 64 * SEQ;
  const us* ktg  = kta + bhbase * 8;
  const us* vthg = vth + bhbase;
  const us* vtlg = vtl + bhbase;

  const int rl   = lane >> 3;
  const int chx  = ((lane & 7) ^ rl) * 8;          // K pre-swizzled src slot
  const int vdr  = lane >> 2;                      // V row within 16-group
  const int vchx = ((lane & 3) ^ (vdr & 3)) * 8;   // V pre-swizzled src slot
  const int dsl0 = (agrp ^ (arow & 7)) * 8;        // K read slot, pass 0
  const int dsl1 = ((4 + agrp) ^ (arow & 7)) * 8;  // pass 1
  const int psl  = (agrp ^ (arow & 3)) * 8;        // P/V read slot
  us* myP = &lP[wave][0];

#define ASTAGE(buf, t32) do { \
    const int kk0 = (t32) * 32; \
    _Pragma("unroll") \
    for (int g = 0; g < 4; ++g) \
      GLDS(kgp + (size_t)(kk0 + 8 * g + rl) * 64 + chx, &lK[buf][g * 512]); \
    _Pragma("unroll") \
    for (int g = 0; g < 4; ++g) \
      GLDS(vgp + (size_t)(16 * g + vdr) * SEQ + kk0 + vchx, &lV[buf][g * 512]); \
    if (lane < 32) GLDS(ktg + (size_t)(kk0 + lane) * 8, &lKt[buf][0]); \
    if (lane < 4)  GLDS(vthg + kk0 + lane * 8, &lVt[buf][0]); \
    if (lane < 4)  GLDS(vtlg + kk0 + lane * 8, &lVt[buf][32]); \
  } while (0)

  short8 ones8;
#pragma unroll
  for (int j = 0; j < 8; ++j) ones8[j] = (short)0x3F80;

  for (int seg = 0; seg < 2; ++seg) {
    const int qb = seg ? (31 - xb) : xb;
    const int q0 = qb * 64;
    const int nt = qb + 1;             // k32-tiles in this half
    const int tstart = hf * nt;
    const int wq = wave * 16 + arow;
    const int qg = q0 + wq;

    ASTAGE(0, tstart);

    // Q fragments (registers, whole segment)
    const us* qp = qs + (bhbase + q0 + wq) * 64;
    short8 qf0 = *(const short8*)(qp + agrp * 8);
    short8 qf1 = *(const short8*)(qp + 32 + agrp * 8);
    float qtv = qt[bhbase + q0 + wq];
    us qh = f2b(qtv);
    us ql = f2b(qtv - b2f(qh));
    short8 qf2 = {};
    if (agrp == 0) { qf2[0] = (short)qh; qf2[1] = (short)qh; qf2[2] = (short)ql; }

    float m_ = 0.0f;                   // upper bound on logits (a*cinner < 0)
    f32x4 acc[5] = {};

    for (int it = 0; it < nt; ++it) {
      const int t = tstart + it;
      const int cur = it & 1;
      if (it < nt - 1) {
        ASTAGE(cur ^ 1, t + 1);
        asm volatile("s_waitcnt vmcnt(11)");
      } else {
        asm volatile("s_waitcnt vmcnt(0)");
      }
      __builtin_amdgcn_s_barrier();

      const us* Kb  = lK[cur];
      const us* Vb  = lV[cur];
      const us* Ktb = lKt[cur];
      const us* Vtb = lVt[cur];

      // ---- S^T = K' Q'^T (augmented: includes -qt*kt) ----
      f32x4 sS[2] = {};
      __builtin_amdgcn_s_setprio(1);
#pragma unroll
      for (int c = 0; c < 2; ++c) {
        short8 kf = *(const short8*)&Kb[(c * 16 + arow) * 64 + dsl0];
        sS[c] = __builtin_amdgcn_mfma_f32_16x16x32_bf16(kf, qf0, sS[c], 0, 0, 0);
      }
#pragma unroll
      for (int c = 0; c < 2; ++c) {
        short8 kf = *(const short8*)&Kb[(c * 16 + arow) * 64 + dsl1];
        sS[c] = __builtin_amdgcn_mfma_f32_16x16x32_bf16(kf, qf1, sS[c], 0, 0, 0);
      }
#pragma unroll
      for (int c = 0; c < 2; ++c) {
        short8 kf2 = {};
        if (agrp == 0) kf2 = *(const short8*)&Ktb[(c * 16 + arow) * 8];
        sS[c] = __builtin_amdgcn_mfma_f32_16x16x32_bf16(kf2, qf2, sS[c], 0, 0, 0);
      }
      __builtin_amdgcn_s_setprio(0);

      if (t >= 2 * qb) {   // tiles that straddle the diagonal
        const int kb = t * 32;
#pragma unroll
        for (int c = 0; c < 2; ++c)
#pragma unroll
          for (int r = 0; r < 4; ++r)
            if (kb + c * 16 + agrp * 4 + r > qg) sS[c][r] = MASKV;
      }

      // ---- online softmax with defer-max (lane owns q=arow; 8 k-values) ----
      float mx = fmaxf(fmaxf(fmaxf(sS[0][0], sS[0][1]), fmaxf(sS[0][2], sS[0][3])),
                       fmaxf(fmaxf(sS[1][0], sS[1][1]), fmaxf(sS[1][2], sS[1][3])));
      mx = fmaxf(mx, __shfl_xor(mx, 16));
      mx = fmaxf(mx, __shfl_xor(mx, 32));
      if (__any(mx > m_ + 20.0f)) {
        float mn = fmaxf(m_, mx);
        float fac = exp2f(al2 * (m_ - mn));
        m_ = mn;
#pragma unroll
        for (int r = 0; r < 4; ++r) {
          float facr = __shfl(fac, agrp * 4 + r);
          acc[0][r] *= facr; acc[1][r] *= facr; acc[2][r] *= facr;
          acc[3][r] *= facr; acc[4][r] *= facr;
        }
      }
      const float alm = al2 * m_;
#pragma unroll
      for (int c = 0; c < 2; ++c)
#pragma unroll
        for (int r = 0; r < 4; ++r)
          sS[c][r] = exp2f(fmaf(al2, sS[c][r], -alm));

      // ---- P -> bf16 -> wave-private swizzled LDS (b64 writes) ----
#pragma unroll
      for (int c = 0; c < 2; ++c) {
        uint2v w;
        w[0] = pk2(sS[c][0], sS[c][1]);
        w[1] = pk2(sS[c][2], sS[c][3]);
        int g = c * 2 + (agrp >> 1);
        int eW = ((g ^ (arow & 3)) * 8) + (agrp & 1) * 4;
        *(uint2v*)&myP[arow * 32 + eW] = w;
      }

      // ---- PV (augmented with [vt_hi, vt_lo, ones] -> tsum & lsum) ----
      __builtin_amdgcn_s_setprio(1);
      short8 pf = *(const short8*)&myP[arow * 32 + psl];
#pragma unroll
      for (int dc = 0; dc < 4; ++dc) {
        short8 vf = *(const short8*)&Vb[(dc * 16 + arow) * 32 + psl];
        acc[dc] = __builtin_amdgcn_mfma_f32_16x16x32_bf16(pf, vf, acc[dc], 0, 0, 0);
      }
      short8 vf4 = {};
      if (arow < 2)  vf4 = *(const short8*)&Vtb[arow * 32 + agrp * 8];
      if (arow == 2) vf4 = ones8;
      acc[4] = __builtin_amdgcn_mfma_f32_16x16x32_bf16(pf, vf4, acc[4], 0, 0, 0);
      __builtin_amdgcn_s_setprio(0);

      __builtin_amdgcn_s_barrier();   // reads done: safe to overwrite other buf
    }

    // ---- epilogue: write un-normalized partial ----
    const size_t pb = ((size_t)(bh * 32 + qb) * 2 + hf) * 64;
#pragma unroll
    for (int r = 0; r < 4; ++r) {
      float t0 = __shfl(acc[4][r], (agrp << 4) | 0);
      float t1 = __shfl(acc[4][r], (agrp << 4) | 1);
      float ls = __shfl(acc[4][r], (agrp << 4) | 2);
      float mr = __shfl(m_, agrp * 4 + r);
      size_t rp = (pb + wave * 16 + agrp * 4 + r) * 68;
#pragma unroll
      for (int dc = 0; dc < 4; ++dc)
        part[rp + dc * 16 + arow] = acc[dc][r];
      if (arow == 0) {
        part[rp + 64] = t0 + t1;
        part[rp + 65] = ls;
        part[rp + 66] = mr;
      }
    }
  }
}

// ---------------------------------------------------------------------------
// Kernel 4: merge split-k partials, mean over heads, Lorentz normalization.
// One wave per (b,s); lane = space dim d. Empty halves have L=0 (exact merge).
// ---------------------------------------------------------------------------
__global__ __launch_bounds__(256) void finalize_kernel(
    const float* __restrict__ part, const float* __restrict__ scale_p,
    float* __restrict__ out)
{
  const int tid  = threadIdx.x;
  const int lane = tid & 63;
  const int gw = blockIdx.x * 4 + (tid >> 6);
  const int b = gw >> 11, si = gw & (SEQ - 1);
  const int qb = si >> 6, row = si & 63;
  const float al2 = (2.0f / scale_p[0]) * 1.44269504088896f;

  float vsum = 0.f, tsum = 0.f;
#pragma unroll
  for (int h = 0; h < NH; ++h) {
    const size_t tile = (size_t)(b * NH + h) * 32 + qb;
    const size_t b0 = (tile * 2 * 64 + row) * 68;
    const size_t b1 = ((tile * 2 + 1) * 64 + row) * 68;
    float A1 = part[b0 + lane];
    float A2 = part[b1 + lane];
    float T1 = part[b0 + 64], L1 = part[b0 + 65], M1 = part[b0 + 66];
    float T2 = part[b1 + 64], L2 = part[b1 + 65], M2 = part[b1 + 66];
    float ms = fmaxf(M1, M2);
    float f1 = exp2f(al2 * (M1 - ms));
    float f2 = exp2f(al2 * (M2 - ms));
    float inv = 1.0f / (f1 * L1 + f2 * L2);
    vsum = fmaf(fmaf(f1, A1, f2 * A2), inv, vsum);
    tsum = fmaf(fmaf(f1, T1, f2 * T2), inv, tsum);
  }
  float ave  = vsum * 0.125f;
  float tave = tsum * 0.125f;
  float contrib = ave * ave;
  if (lane == 0) contrib -= tave * tave;
  contrib += __shfl_xor(contrib, 1);
  contrib += __shfl_xor(contrib, 2);
  contrib += __shfl_xor(contrib, 4);
  contrib += __shfl_xor(contrib, 8);
  contrib += __shfl_xor(contrib, 16);
  contrib += __shfl_xor(contrib, 32);
  float denom = sqrtf(fmaxf(fabsf(contrib), 1e-8f));
  size_t ob = ((size_t)b * SEQ + si) * (size_t)DD;
  out[ob + 1 + lane] = ave / denom;
  if (lane == 0) out[ob] = tave / denom;
}

// ---------------------------------------------------------------------------
extern "C" void kernel_launch(void* const* d_in, const int* in_sizes, int n_in,
                              void* d_out, int out_size, void* d_ws, size_t ws_size,
                              hipStream_t stream) {
  const float* Xq  = (const float*)d_in[0];
  const float* Xs  = (const float*)d_in[1];
  const float* Wq  = (const float*)d_in[2];
  const float* Bq  = (const float*)d_in[3];
  const float* Wk  = (const float*)d_in[4];
  const float* Bk  = (const float*)d_in[5];
  const float* Wv  = (const float*)d_in[6];
  const float* Bv  = (const float*)d_in[7];
  const float* scale = (const float*)d_in[8];
  float* out = (float*)d_out;

  char* p = (char*)d_ws;
  const size_t NROW = (size_t)BATCH * NH * SEQ;   // 65536

  // Region 0 (35.7 MB): partials, overlapped with bf16 X and W copies
  // (proj consumes Xb/Wb before attn writes part).
  float* part = (float*)p;
  us* Xqb   = (us*)p;
  us* Xsb   = (us*)(p + 16777216);
  us* Wqb16 = (us*)(p + 33554432);
  us* Wkb16 = (us*)(p + 34078720);
  us* Wvb16 = (us*)(p + 34603008);
  p += (size_t)1024 * 2 * 64 * 68 * 4;             // 35,651,584
  us* qsb = (us*)p; p += NROW * 64 * 2;
  us* ksb = (us*)p; p += NROW * 64 * 2;
  us* vsb = (us*)p; p += NROW * 64 * 2;
  us* vTb = (us*)p; p += NROW * 64 * 2;
  float* qtb = (float*)p; p += NROW * 4;
  us* ktaw = (us*)p; p += NROW * 8 * 2;
  us* vthw = (us*)p; p += NROW * 2;
  us* vtlw = (us*)p; p += NROW * 2;

  tobf16_kernel<<<dim3(1024, 5), 256, 0, stream>>>(
      Xq, Xs, Wq, Wk, Wv, Xqb, Xsb, Wqb16, Wkb16, Wvb16);
  proj_kernel<<<dim3(128, NH, 3), 256, 0, stream>>>(
      Xqb, Xsb, Wqb16, Wkb16, Wvb16, Bq, Bk, Bv,
      qsb, qtb, ksb, ktaw, vsb, vthw, vtlw);
  transpose_v_kernel<<<dim3(SEQ / 64, BATCH * NH), 256, 0, stream>>>(vsb, vTb);
  attn_kernel<<<dim3(1024), 256, 0, stream>>>(
      qsb, qtb, ksb, ktaw, vTb, vthw, vtlw, scale, part);
  finalize_kernel<<<(BATCH * SEQ) / 4, 256, 0, stream>>>(part, scale, out);
}

// Round 6
// 97.635 us; speedup vs baseline: 1.7141x; 1.7141x over previous
//
#include <hip/hip_runtime.h>

// Problem constants
#define BATCH 4
#define SEQ   2048
#define INC   512
#define NH    8
#define OUTC  64      // space dim; head dim = 65
#define DD    65
#define NROW  (BATCH * NH * SEQ)   // 65536

typedef float f32x4 __attribute__((ext_vector_type(4)));
typedef short short8 __attribute__((ext_vector_type(8)));
typedef short short4v __attribute__((ext_vector_type(4)));
typedef unsigned int uint2v __attribute__((ext_vector_type(2)));
typedef unsigned short us;

static __device__ __forceinline__ us f2b(float f) {
  unsigned int u = __float_as_uint(f);
  u = (u + 0x7FFFu + ((u >> 16) & 1u)) >> 16;   // RNE f32->bf16
  return (us)u;
}
static __device__ __forceinline__ float b2f(us h) {
  return __uint_as_float(((unsigned int)h) << 16);
}
static __device__ __forceinline__ unsigned int pk2(float lo, float hi) {
  unsigned int r;
  asm("v_cvt_pk_bf16_f32 %0, %1, %2" : "=v"(r) : "v"(lo), "v"(hi));
  return r;
}

#define GLDS(g, l) __builtin_amdgcn_global_load_lds( \
    (const __attribute__((address_space(1))) void*)(g), \
    (__attribute__((address_space(3))) void*)(l), 16, 0, 0)

// ---------------------------------------------------------------------------
// Kernel 0: f32 -> bf16 conversion for X (both) and W (all three).
// ---------------------------------------------------------------------------
__global__ __launch_bounds__(256) void tobf16_kernel(
    const float* __restrict__ Xq, const float* __restrict__ Xs,
    const float* __restrict__ Wq, const float* __restrict__ Wk,
    const float* __restrict__ Wv,
    us* __restrict__ dXq, us* __restrict__ dXs,
    us* __restrict__ dWq, us* __restrict__ dWk, us* __restrict__ dWv)
{
  const int which = blockIdx.y;
  const float* src;
  us* dst;
  int n;
  switch (which) {
    case 0: src = Xq; dst = dXq; n = BATCH * SEQ * INC; break;
    case 1: src = Xs; dst = dXs; n = BATCH * SEQ * INC; break;
    case 2: src = Wq; dst = dWq; n = NH * OUTC * INC; break;
    case 3: src = Wk; dst = dWk; n = NH * OUTC * INC; break;
    default: src = Wv; dst = dWv; n = NH * OUTC * INC; break;
  }
  for (long i = (long)blockIdx.x * 256 + threadIdx.x; i * 4 < n;
       i += (long)gridDim.x * 256) {
    f32x4 v = *(const f32x4*)(src + i * 4);
    short4v o;
    o[0] = (short)f2b(v[0]); o[1] = (short)f2b(v[1]);
    o[2] = (short)f2b(v[2]); o[3] = (short)f2b(v[3]);
    *(short4v*)(dst + i * 4) = o;
  }
}

// ---------------------------------------------------------------------------
// Kernel 1: per-head projections from bf16 inputs, GLDS double-buffered.
// Outputs: space part bf16 [B,H,S,64]; per kind:
//   Q: qt f32 [NROW];  K: kta u32 [NROW] = (-kh)|(-kl)<<16;
//   V: vtc bf16 [2][NROW] = {hi plane, lo plane}
// ---------------------------------------------------------------------------
__global__ __launch_bounds__(256) void proj_kernel(
    const us* __restrict__ Xqb, const us* __restrict__ Xsb,
    const us* __restrict__ Wqb, const us* __restrict__ Wkb, const us* __restrict__ Wvb,
    const float* __restrict__ Bq, const float* __restrict__ Bk, const float* __restrict__ Bv,
    us* __restrict__ qs, float* __restrict__ qt,
    us* __restrict__ ks, unsigned int* __restrict__ kta,
    us* __restrict__ vs, us* __restrict__ vtc)
{
  const int which = blockIdx.z;
  const us* X = (which == 0) ? Xqb : Xsb;
  const us* W = (which == 0) ? Wqb : (which == 1 ? Wkb : Wvb);
  const float* Bb = (which == 0) ? Bq : (which == 1 ? Bk : Bv);
  us* outs = (which == 0) ? qs : (which == 1 ? ks : vs);

  const int m0 = blockIdx.x * 64;
  const int h  = blockIdx.y;
  const int n0 = h * 64;

  __shared__ alignas(16) us lX[2][64 * 64];
  __shared__ alignas(16) us lW[2][64 * 64];

  const int tid  = threadIdx.x;
  const int lane = tid & 63;
  const int wave = tid >> 6;
  const int arow = lane & 15;
  const int agrp = lane >> 4;
  const int rl   = lane >> 3;
  const int chx  = ((lane & 7) ^ rl) * 8;
  const int r0   = wave * 8 + rl;
  const int r1   = r0 + 32;

#define PSTAGE(buf, k0) do { \
    GLDS(X + (size_t)(m0 + r0) * INC + (k0) + chx, &lX[buf][wave * 512]); \
    GLDS(X + (size_t)(m0 + r1) * INC + (k0) + chx, &lX[buf][2048 + wave * 512]); \
    GLDS(W + (size_t)(n0 + r0) * INC + (k0) + chx, &lW[buf][wave * 512]); \
    GLDS(W + (size_t)(n0 + r1) * INC + (k0) + chx, &lW[buf][2048 + wave * 512]); \
  } while (0)

  f32x4 acc[4] = {};
  PSTAGE(0, 0);

  for (int kk = 0; kk < 8; ++kk) {
    const int cur = kk & 1;
    if (kk < 7) {
      PSTAGE(cur ^ 1, (kk + 1) * 64);
      asm volatile("s_waitcnt vmcnt(4)");
    } else {
      asm volatile("s_waitcnt vmcnt(0)");
    }
    __builtin_amdgcn_s_barrier();
#pragma unroll
    for (int kc = 0; kc < 2; ++kc) {
      short8 af = *(const short8*)&lX[cur][(wave * 16 + arow) * 64 + (((kc * 4 + agrp) ^ (arow & 7)) * 8)];
#pragma unroll
      for (int c = 0; c < 4; ++c) {
        short8 bf = *(const short8*)&lW[cur][(c * 16 + arow) * 64 + (((kc * 4 + agrp) ^ (arow & 7)) * 8)];
        acc[c] = __builtin_amdgcn_mfma_f32_16x16x32_bf16(af, bf, acc[c], 0, 0, 0);
      }
    }
    __builtin_amdgcn_s_barrier();
  }

  float bcol[4];
#pragma unroll
  for (int c = 0; c < 4; ++c) bcol[c] = Bb[n0 + c * 16 + arow];
#pragma unroll
  for (int r = 0; r < 4; ++r) {
    float s2 = 0.f;
#pragma unroll
    for (int c = 0; c < 4; ++c) {
      float v = acc[c][r] + bcol[c];
      acc[c][r] = v;
      s2 += v * v;
    }
    s2 += __shfl_xor(s2, 1); s2 += __shfl_xor(s2, 2);
    s2 += __shfl_xor(s2, 4); s2 += __shfl_xor(s2, 8);
    float tv = sqrtf(s2 + 1.0f);
    int gs = m0 + wave * 16 + agrp * 4 + r;
    int bi = gs >> 11, si = gs & (SEQ - 1);
    size_t rowbase = (size_t)(bi * NH + h) * SEQ + si;
    size_t obase = rowbase * 64;
#pragma unroll
    for (int c = 0; c < 4; ++c) outs[obase + c * 16 + arow] = f2b(acc[c][r]);
    if (arow == 0) {
      if (which == 0) {
        qt[rowbase] = tv;
      } else {
        us th = f2b(tv);
        us tl = f2b(tv - b2f(th));
        if (which == 1) {
          kta[rowbase] = (unsigned int)(us)(th ^ 0x8000)
                       | ((unsigned int)(us)(tl ^ 0x8000) << 16);
        } else {
          vtc[rowbase] = th;
          vtc[NROW + rowbase] = tl;
        }
      }
    }
  }
}

// ---------------------------------------------------------------------------
// Kernel 2: transpose V space-part per (b,h): [S,64] -> [64,S]  (bf16)
// ---------------------------------------------------------------------------
__global__ __launch_bounds__(256) void transpose_v_kernel(
    const us* __restrict__ vs, us* __restrict__ vT)
{
  const int bh = blockIdx.y;
  const int s0 = blockIdx.x * 64;
  __shared__ us lT[64 * 80];
  const int tid = threadIdx.x;
#pragma unroll
  for (int u0 = 0; u0 < 2; ++u0) {
    int u = tid + u0 * 256;
    int row = u >> 3, ch = u & 7;
    short8 v = *(const short8*)&vs[((size_t)bh * SEQ + s0 + row) * 64 + ch * 8];
    *(short8*)&lT[row * 80 + ch * 8] = v;
  }
  __syncthreads();
#pragma unroll
  for (int u0 = 0; u0 < 2; ++u0) {
    int u = tid + u0 * 256;
    int o = u >> 3, sc = u & 7;
    short8 w;
#pragma unroll
    for (int j = 0; j < 8; ++j) w[j] = lT[(sc * 8 + j) * 80 + o];
    *(short8*)&vT[((size_t)bh * 64 + o) * SEQ + s0 + sc * 8] = w;
  }
}

// ---------------------------------------------------------------------------
// Kernel 3: 2-way split-k causal flash attention, KBLK=64, 1024 blocks.
// Block (xb, hf, bh): segs {qb=xb, qb=31-xb}; per seg hf=0 takes k-tiles
// [0, ceil((qb+1)/2)), hf=1 the rest (incl. diagonal). 17/16 tiles/block.
// No max tracking: logits = a*cinner <= 0, so P = exp2(al2*s) directly
// (proven numerics: round-5 path never updated m from 0). Partials
// [rows 64][68]: 64 space, tsum, lsum, M=0.
// ---------------------------------------------------------------------------
__global__ __launch_bounds__(256, 4) void attn_kernel(
    const us* __restrict__ qs, const float* __restrict__ qt,
    const us* __restrict__ ks, const unsigned int* __restrict__ kta,
    const us* __restrict__ vT, const us* __restrict__ vtc,
    const float* __restrict__ scale_p, float* __restrict__ part)
{
  // XCD-aware swizzle: 32 blocks of one bh land on one XCD.
  const int f = blockIdx.x;
  const int xcd = f & 7, idx = f >> 3;
  const int bh = xcd * 4 + (idx >> 5);
  const int inner = idx & 31;
  const int xb = inner >> 1;
  const int hf = inner & 1;
  const float al2 = (2.0f / scale_p[0]) * 1.44269504088896f;  // a * log2(e)

  __shared__ alignas(16) us lK[2][64 * 64];
  __shared__ alignas(16) us lV[2][64 * 64];
  __shared__ alignas(16) us lP[4][16 * 40];   // 80B rows, 16B-aligned

  const int tid  = threadIdx.x;
  const int lane = tid & 63;
  const int wave = tid >> 6;
  const int arow = lane & 15;
  const int agrp = lane >> 4;

  const size_t bhbase = (size_t)bh * SEQ;
  const us* kgp = ks + bhbase * 64;
  const us* vgp = vT + (size_t)bh * 64 * SEQ;
  const unsigned int* ktp = kta + bhbase;
  const us* vtp = vtc + (size_t)(arow & 1) * NROW + bhbase;

  const int rl   = lane >> 3;
  const int chx  = ((lane & 7) ^ rl) * 8;
  const int r0s  = wave * 8 + rl;
  const int r1s  = r0s + 32;
  const int dsl0 = (agrp ^ (arow & 7)) * 8;
  const int dsl1 = ((4 + agrp) ^ (arow & 7)) * 8;
  us* myP = &lP[wave][0];
  const int pw0 = arow * 40 + agrp * 4;   // b64 write slot (c2=0); +16 for c2=1
  const int prd = arow * 40 + agrp * 8;   // b128 read slot

#define ASTAGE(buf, t64) do { \
    const int kk0 = (t64) * 64; \
    GLDS(kgp + (size_t)(kk0 + r0s) * 64 + chx, &lK[buf][wave * 512]); \
    GLDS(kgp + (size_t)(kk0 + r1s) * 64 + chx, &lK[buf][2048 + wave * 512]); \
    GLDS(vgp + (size_t)r0s * SEQ + kk0 + chx, &lV[buf][wave * 512]); \
    GLDS(vgp + (size_t)r1s * SEQ + kk0 + chx, &lV[buf][2048 + wave * 512]); \
  } while (0)

  short8 ones8, zero8 = {};
#pragma unroll
  for (int j = 0; j < 8; ++j) ones8[j] = (short)0x3F80;

  for (int seg = 0; seg < 2; ++seg) {
    const int qb = seg ? (31 - xb) : xb;
    const int q0 = qb * 64;
    const int c0 = (qb + 2) >> 1;           // ceil((qb+1)/2)
    const int t_lo = hf ? c0 : 0;
    const int t_hi = hf ? (qb + 1) : c0;
    const int nt = t_hi - t_lo;
    const int wq = wave * 16 + arow;

    f32x4 acc[5] = {};

    if (nt > 0) {
      ASTAGE(0, t_lo);

      // Q fragments (registers, whole segment)
      const us* qp = qs + (bhbase + q0 + wq) * 64;
      short8 qf0 = *(const short8*)(qp + agrp * 8);
      short8 qf1 = *(const short8*)(qp + 32 + agrp * 8);
      float qtv = qt[bhbase + q0 + wq];
      us qh = f2b(qtv);
      us ql = f2b(qtv - b2f(qh));
      short8 qf2 = {};
      if (agrp == 0) { qf2[0] = (short)qh; qf2[1] = (short)qh; qf2[2] = (short)ql; }

      // aug regs for first tile (kta packed u32 per k-row; vt hi/lo slices)
      unsigned int ka[4];
      short8 va0, va1;
      {
        const int kk0 = t_lo * 64;
#pragma unroll
        for (int c = 0; c < 4; ++c) ka[c] = ktp[kk0 + c * 16 + arow];
        va0 = *(const short8*)(vtp + kk0 + agrp * 8);
        va1 = *(const short8*)(vtp + kk0 + 32 + agrp * 8);
      }

      for (int it = 0; it < nt; ++it) {
        const int t = t_lo + it;
        const int cur = it & 1;
        if (it < nt - 1) {
          ASTAGE(cur ^ 1, t + 1);
          asm volatile("s_waitcnt vmcnt(4)");
        } else {
          asm volatile("s_waitcnt vmcnt(0)");
        }
        __builtin_amdgcn_s_barrier();

        const us* Kb = lK[cur];
        const us* Vb = lV[cur];

        // ---- S^T = K' Q'^T (augmented: includes -qt*kt hi/lo) ----
        f32x4 sS[4] = {};
        __builtin_amdgcn_s_setprio(1);
#pragma unroll
        for (int c = 0; c < 4; ++c) {
          short8 kf = *(const short8*)&Kb[(c * 16 + arow) * 64 + dsl0];
          sS[c] = __builtin_amdgcn_mfma_f32_16x16x32_bf16(kf, qf0, sS[c], 0, 0, 0);
        }
#pragma unroll
        for (int c = 0; c < 4; ++c) {
          short8 kf = *(const short8*)&Kb[(c * 16 + arow) * 64 + dsl1];
          sS[c] = __builtin_amdgcn_mfma_f32_16x16x32_bf16(kf, qf1, sS[c], 0, 0, 0);
        }
#pragma unroll
        for (int c = 0; c < 4; ++c) {
          short8 kf2 = {};
          if (agrp == 0) {
            unsigned int w0 = ka[c];
            kf2[0] = (short)(w0 & 0xFFFFu);
            kf2[1] = (short)(w0 >> 16);
            kf2[2] = (short)(w0 & 0xFFFFu);
          }
          sS[c] = __builtin_amdgcn_mfma_f32_16x16x32_bf16(kf2, qf2, sS[c], 0, 0, 0);
        }
        __builtin_amdgcn_s_setprio(0);

        // ---- P = exp2(al2 * logit); causal-mask -> exact 0 ----
#pragma unroll
        for (int c = 0; c < 4; ++c)
#pragma unroll
          for (int r = 0; r < 4; ++r)
            sS[c][r] = exp2f(al2 * sS[c][r]);
        if (t == qb) {
#pragma unroll
          for (int c = 0; c < 4; ++c)
#pragma unroll
            for (int r = 0; r < 4; ++r)
              if (c * 16 + agrp * 4 + r > wq) sS[c][r] = 0.f;
        }

        // ---- PV: 2 phases over kc, wave-private 1KB P tile reused ----
        {
          uint2v w;
          w[0] = pk2(sS[0][0], sS[0][1]); w[1] = pk2(sS[0][2], sS[0][3]);
          *(uint2v*)&myP[pw0] = w;
          w[0] = pk2(sS[1][0], sS[1][1]); w[1] = pk2(sS[1][2], sS[1][3]);
          *(uint2v*)&myP[pw0 + 16] = w;
          short8 pf = *(const short8*)&myP[prd];
          __builtin_amdgcn_s_setprio(1);
#pragma unroll
          for (int dc = 0; dc < 4; ++dc) {
            short8 vf = *(const short8*)&Vb[(dc * 16 + arow) * 64 + dsl0];
            acc[dc] = __builtin_amdgcn_mfma_f32_16x16x32_bf16(pf, vf, acc[dc], 0, 0, 0);
          }
          short8 vf4 = (arow < 2) ? va0 : ((arow == 2) ? ones8 : zero8);
          acc[4] = __builtin_amdgcn_mfma_f32_16x16x32_bf16(pf, vf4, acc[4], 0, 0, 0);
          __builtin_amdgcn_s_setprio(0);
        }
        {
          uint2v w;
          w[0] = pk2(sS[2][0], sS[2][1]); w[1] = pk2(sS[2][2], sS[2][3]);
          *(uint2v*)&myP[pw0] = w;
          w[0] = pk2(sS[3][0], sS[3][1]); w[1] = pk2(sS[3][2], sS[3][3]);
          *(uint2v*)&myP[pw0 + 16] = w;
          short8 pf = *(const short8*)&myP[prd];
          __builtin_amdgcn_s_setprio(1);
#pragma unroll
          for (int dc = 0; dc < 4; ++dc) {
            short8 vf = *(const short8*)&Vb[(dc * 16 + arow) * 64 + dsl1];
            acc[dc] = __builtin_amdgcn_mfma_f32_16x16x32_bf16(pf, vf, acc[dc], 0, 0, 0);
          }
          short8 vf4 = (arow < 2) ? va1 : ((arow == 2) ? ones8 : zero8);
          acc[4] = __builtin_amdgcn_mfma_f32_16x16x32_bf16(pf, vf4, acc[4], 0, 0, 0);
          __builtin_amdgcn_s_setprio(0);
        }

        // aug prefetch for next tile (drained by next iteration's vmcnt)
        if (it + 1 < nt) {
          const int kk0 = (t + 1) * 64;
#pragma unroll
          for (int c = 0; c < 4; ++c) ka[c] = ktp[kk0 + c * 16 + arow];
          va0 = *(const short8*)(vtp + kk0 + agrp * 8);
          va1 = *(const short8*)(vtp + kk0 + 32 + agrp * 8);
        }

        __builtin_amdgcn_s_barrier();   // reads done: safe to overwrite other buf
      }
    }

    // ---- epilogue: write un-normalized partial (zeros for empty seg) ----
    const size_t pb = ((size_t)(bh * 32 + qb) * 2 + hf) * 64;
#pragma unroll
    for (int r = 0; r < 4; ++r) {
      float t0 = __shfl(acc[4][r], (agrp << 4) | 0);
      float t1 = __shfl(acc[4][r], (agrp << 4) | 1);
      float ls = __shfl(acc[4][r], (agrp << 4) | 2);
      size_t rp = (pb + wave * 16 + agrp * 4 + r) * 68;
#pragma unroll
      for (int dc = 0; dc < 4; ++dc)
        part[rp + dc * 16 + arow] = acc[dc][r];
      if (arow == 0) {
        part[rp + 64] = t0 + t1;
        part[rp + 65] = ls;
        part[rp + 66] = 0.0f;
      }
    }
  }
}

// ---------------------------------------------------------------------------
// Kernel 4: merge split-k partials, mean over heads, Lorentz normalization.
// One wave per (b,s); lane = space dim d. Empty halves have L=0 (exact).
// ---------------------------------------------------------------------------
__global__ __launch_bounds__(256) void finalize_kernel(
    const float* __restrict__ part, const float* __restrict__ scale_p,
    float* __restrict__ out)
{
  const int tid  = threadIdx.x;
  const int lane = tid & 63;
  const int gw = blockIdx.x * 4 + (tid >> 6);
  const int b = gw >> 11, si = gw & (SEQ - 1);
  const int qb = si >> 6, row = si & 63;
  const float al2 = (2.0f / scale_p[0]) * 1.44269504088896f;

  float vsum = 0.f, tsum = 0.f;
#pragma unroll
  for (int h = 0; h < NH; ++h) {
    const size_t tile = (size_t)(b * NH + h) * 32 + qb;
    const size_t b0 = (tile * 2 * 64 + row) * 68;
    const size_t b1 = ((tile * 2 + 1) * 64 + row) * 68;
    float A1 = part[b0 + lane];
    float A2 = part[b1 + lane];
    float T1 = part[b0 + 64], L1 = part[b0 + 65], M1 = part[b0 + 66];
    float T2 = part[b1 + 64], L2 = part[b1 + 65], M2 = part[b1 + 66];
    float ms = fmaxf(M1, M2);
    float f1 = exp2f(al2 * (M1 - ms));
    float f2 = exp2f(al2 * (M2 - ms));
    float inv = 1.0f / (f1 * L1 + f2 * L2);
    vsum = fmaf(fmaf(f1, A1, f2 * A2), inv, vsum);
    tsum = fmaf(fmaf(f1, T1, f2 * T2), inv, tsum);
  }
  float ave  = vsum * 0.125f;
  float tave = tsum * 0.125f;
  float contrib = ave * ave;
  if (lane == 0) contrib -= tave * tave;
  contrib += __shfl_xor(contrib, 1);
  contrib += __shfl_xor(contrib, 2);
  contrib += __shfl_xor(contrib, 4);
  contrib += __shfl_xor(contrib, 8);
  contrib += __shfl_xor(contrib, 16);
  contrib += __shfl_xor(contrib, 32);
  float denom = sqrtf(fmaxf(fabsf(contrib), 1e-8f));
  size_t ob = ((size_t)b * SEQ + si) * (size_t)DD;
  out[ob + 1 + lane] = ave / denom;
  if (lane == 0) out[ob] = tave / denom;
}

// ---------------------------------------------------------------------------
extern "C" void kernel_launch(void* const* d_in, const int* in_sizes, int n_in,
                              void* d_out, int out_size, void* d_ws, size_t ws_size,
                              hipStream_t stream) {
  const float* Xq  = (const float*)d_in[0];
  const float* Xs  = (const float*)d_in[1];
  const float* Wq  = (const float*)d_in[2];
  const float* Bq  = (const float*)d_in[3];
  const float* Wk  = (const float*)d_in[4];
  const float* Bk  = (const float*)d_in[5];
  const float* Wv  = (const float*)d_in[6];
  const float* Bv  = (const float*)d_in[7];
  const float* scale = (const float*)d_in[8];
  float* out = (float*)d_out;

  char* p = (char*)d_ws;

  // Region 0 (35.7 MB): partials, overlapped with bf16 X and W copies
  // (proj consumes Xb/Wb before attn writes part).
  float* part = (float*)p;
  us* Xqb   = (us*)p;
  us* Xsb   = (us*)(p + 16777216);
  us* Wqb16 = (us*)(p + 33554432);
  us* Wkb16 = (us*)(p + 34078720);
  us* Wvb16 = (us*)(p + 34603008);
  p += (size_t)1024 * 2 * 64 * 68 * 4;             // 35,651,584
  us* qsb = (us*)p; p += (size_t)NROW * 64 * 2;
  us* ksb = (us*)p; p += (size_t)NROW * 64 * 2;
  us* vsb = (us*)p; p += (size_t)NROW * 64 * 2;
  us* vTb = (us*)p; p += (size_t)NROW * 64 * 2;
  float* qtb = (float*)p; p += (size_t)NROW * 4;
  unsigned int* ktaw = (unsigned int*)p; p += (size_t)NROW * 4;
  us* vtcw = (us*)p; p += (size_t)NROW * 2 * 2;

  tobf16_kernel<<<dim3(1024, 5), 256, 0, stream>>>(
      Xq, Xs, Wq, Wk, Wv, Xqb, Xsb, Wqb16, Wkb16, Wvb16);
  proj_kernel<<<dim3(128, NH, 3), 256, 0, stream>>>(
      Xqb, Xsb, Wqb16, Wkb16, Wvb16, Bq, Bk, Bv,
      qsb, qtb, ksb, ktaw, vsb, vtcw);
  transpose_v_kernel<<<dim3(SEQ / 64, BATCH * NH), 256, 0, stream>>>(vsb, vTb);
  attn_kernel<<<dim3(1024), 256, 0, stream>>>(
      qsb, qtb, ksb, ktaw, vTb, vtcw, scale, part);
  finalize_kernel<<<(BATCH * SEQ) / 4, 256, 0, stream>>>(part, scale, out);
}

// Round 7
// 95.987 us; speedup vs baseline: 1.7435x; 1.0172x over previous
//
#include <hip/hip_runtime.h>

// Problem constants
#define BATCH 4
#define SEQ   2048
#define INC   512
#define NH    8
#define OUTC  64      // space dim; head dim = 65
#define DD    65
#define NROW  (BATCH * NH * SEQ)   // 65536

typedef float f32x4 __attribute__((ext_vector_type(4)));
typedef short short8 __attribute__((ext_vector_type(8)));
typedef short short4v __attribute__((ext_vector_type(4)));
typedef unsigned int uint2v __attribute__((ext_vector_type(2)));
typedef unsigned short us;

static __device__ __forceinline__ us f2b(float f) {
  unsigned int u = __float_as_uint(f);
  u = (u + 0x7FFFu + ((u >> 16) & 1u)) >> 16;   // RNE f32->bf16
  return (us)u;
}
static __device__ __forceinline__ float b2f(us h) {
  return __uint_as_float(((unsigned int)h) << 16);
}
static __device__ __forceinline__ unsigned int pk2(float lo, float hi) {
  unsigned int r;
  asm("v_cvt_pk_bf16_f32 %0, %1, %2" : "=v"(r) : "v"(lo), "v"(hi));
  return r;
}

#define GLDS(g, l) __builtin_amdgcn_global_load_lds( \
    (const __attribute__((address_space(1))) void*)(g), \
    (__attribute__((address_space(3))) void*)(l), 16, 0, 0)

// ---------------------------------------------------------------------------
// Kernel 0: f32 -> bf16 conversion for X (both) and W (all three).
// ---------------------------------------------------------------------------
__global__ __launch_bounds__(256) void tobf16_kernel(
    const float* __restrict__ Xq, const float* __restrict__ Xs,
    const float* __restrict__ Wq, const float* __restrict__ Wk,
    const float* __restrict__ Wv,
    us* __restrict__ dXq, us* __restrict__ dXs,
    us* __restrict__ dWq, us* __restrict__ dWk, us* __restrict__ dWv)
{
  const int which = blockIdx.y;
  const float* src;
  us* dst;
  int n;
  switch (which) {
    case 0: src = Xq; dst = dXq; n = BATCH * SEQ * INC; break;
    case 1: src = Xs; dst = dXs; n = BATCH * SEQ * INC; break;
    case 2: src = Wq; dst = dWq; n = NH * OUTC * INC; break;
    case 3: src = Wk; dst = dWk; n = NH * OUTC * INC; break;
    default: src = Wv; dst = dWv; n = NH * OUTC * INC; break;
  }
  for (long i = (long)blockIdx.x * 256 + threadIdx.x; i * 4 < n;
       i += (long)gridDim.x * 256) {
    f32x4 v = *(const f32x4*)(src + i * 4);
    short4v o;
    o[0] = (short)f2b(v[0]); o[1] = (short)f2b(v[1]);
    o[2] = (short)f2b(v[2]); o[3] = (short)f2b(v[3]);
    *(short4v*)(dst + i * 4) = o;
  }
}

// ---------------------------------------------------------------------------
// Kernel 1: per-head projections from bf16 inputs, GLDS double-buffered.
// XCD-affinity swizzle: the 8 head-blocks of one X row-tile launch adjacently
// with blockIdx % 8 == m0 % 8  ->  same XCD -> X tile L2-resident across its
// 8 re-reads (was L3 round-trips with h-major dispatch).
// ---------------------------------------------------------------------------
__global__ __launch_bounds__(256) void proj_kernel(
    const us* __restrict__ Xqb, const us* __restrict__ Xsb,
    const us* __restrict__ Wqb, const us* __restrict__ Wkb, const us* __restrict__ Wvb,
    const float* __restrict__ Bq, const float* __restrict__ Bk, const float* __restrict__ Bv,
    us* __restrict__ qs, float* __restrict__ qt,
    us* __restrict__ ks, unsigned int* __restrict__ kta,
    us* __restrict__ vs, us* __restrict__ vtc)
{
  const int which = blockIdx.z;
  const us* X = (which == 0) ? Xqb : Xsb;
  const us* W = (which == 0) ? Wqb : (which == 1 ? Wkb : Wvb);
  const float* Bb = (which == 0) ? Bq : (which == 1 ? Bk : Bv);
  us* outs = (which == 0) ? qs : (which == 1 ? ks : vs);

  const int lin = blockIdx.x;                    // 0..1023
  const int h   = (lin >> 3) & 7;
  const int m0  = (((lin >> 6) << 3) | (lin & 7)) * 64;
  const int n0  = h * 64;

  __shared__ alignas(16) us lX[2][64 * 64];
  __shared__ alignas(16) us lW[2][64 * 64];

  const int tid  = threadIdx.x;
  const int lane = tid & 63;
  const int wave = tid >> 6;
  const int arow = lane & 15;
  const int agrp = lane >> 4;
  const int rl   = lane >> 3;
  const int chx  = ((lane & 7) ^ rl) * 8;
  const int r0   = wave * 8 + rl;
  const int r1   = r0 + 32;

#define PSTAGE(buf, k0) do { \
    GLDS(X + (size_t)(m0 + r0) * INC + (k0) + chx, &lX[buf][wave * 512]); \
    GLDS(X + (size_t)(m0 + r1) * INC + (k0) + chx, &lX[buf][2048 + wave * 512]); \
    GLDS(W + (size_t)(n0 + r0) * INC + (k0) + chx, &lW[buf][wave * 512]); \
    GLDS(W + (size_t)(n0 + r1) * INC + (k0) + chx, &lW[buf][2048 + wave * 512]); \
  } while (0)

  f32x4 acc[4] = {};
  PSTAGE(0, 0);

  for (int kk = 0; kk < 8; ++kk) {
    const int cur = kk & 1;
    if (kk < 7) {
      PSTAGE(cur ^ 1, (kk + 1) * 64);
      asm volatile("s_waitcnt vmcnt(4)");
    } else {
      asm volatile("s_waitcnt vmcnt(0)");
    }
    __builtin_amdgcn_s_barrier();
#pragma unroll
    for (int kc = 0; kc < 2; ++kc) {
      short8 af = *(const short8*)&lX[cur][(wave * 16 + arow) * 64 + (((kc * 4 + agrp) ^ (arow & 7)) * 8)];
#pragma unroll
      for (int c = 0; c < 4; ++c) {
        short8 bf = *(const short8*)&lW[cur][(c * 16 + arow) * 64 + (((kc * 4 + agrp) ^ (arow & 7)) * 8)];
        acc[c] = __builtin_amdgcn_mfma_f32_16x16x32_bf16(af, bf, acc[c], 0, 0, 0);
      }
    }
    __builtin_amdgcn_s_barrier();
  }

  float bcol[4];
#pragma unroll
  for (int c = 0; c < 4; ++c) bcol[c] = Bb[n0 + c * 16 + arow];
#pragma unroll
  for (int r = 0; r < 4; ++r) {
    float s2 = 0.f;
#pragma unroll
    for (int c = 0; c < 4; ++c) {
      float v = acc[c][r] + bcol[c];
      acc[c][r] = v;
      s2 += v * v;
    }
    s2 += __shfl_xor(s2, 1); s2 += __shfl_xor(s2, 2);
    s2 += __shfl_xor(s2, 4); s2 += __shfl_xor(s2, 8);
    float tv = sqrtf(s2 + 1.0f);
    int gs = m0 + wave * 16 + agrp * 4 + r;
    int bi = gs >> 11, si = gs & (SEQ - 1);
    size_t rowbase = (size_t)(bi * NH + h) * SEQ + si;
    size_t obase = rowbase * 64;
#pragma unroll
    for (int c = 0; c < 4; ++c) outs[obase + c * 16 + arow] = f2b(acc[c][r]);
    if (arow == 0) {
      if (which == 0) {
        qt[rowbase] = tv;
      } else {
        us th = f2b(tv);
        us tl = f2b(tv - b2f(th));
        if (which == 1) {
          kta[rowbase] = (unsigned int)(us)(th ^ 0x8000)
                       | ((unsigned int)(us)(tl ^ 0x8000) << 16);
        } else {
          vtc[rowbase] = th;
          vtc[NROW + rowbase] = tl;
        }
      }
    }
  }
}

// ---------------------------------------------------------------------------
// Kernel 2: transpose V space-part per (b,h): [S,64] -> [64,S]  (bf16)
// ---------------------------------------------------------------------------
__global__ __launch_bounds__(256) void transpose_v_kernel(
    const us* __restrict__ vs, us* __restrict__ vT)
{
  const int bh = blockIdx.y;
  const int s0 = blockIdx.x * 64;
  __shared__ us lT[64 * 80];
  const int tid = threadIdx.x;
#pragma unroll
  for (int u0 = 0; u0 < 2; ++u0) {
    int u = tid + u0 * 256;
    int row = u >> 3, ch = u & 7;
    short8 v = *(const short8*)&vs[((size_t)bh * SEQ + s0 + row) * 64 + ch * 8];
    *(short8*)&lT[row * 80 + ch * 8] = v;
  }
  __syncthreads();
#pragma unroll
  for (int u0 = 0; u0 < 2; ++u0) {
    int u = tid + u0 * 256;
    int o = u >> 3, sc = u & 7;
    short8 w;
#pragma unroll
    for (int j = 0; j < 8; ++j) w[j] = lT[(sc * 8 + j) * 80 + o];
    *(short8*)&vT[((size_t)bh * 64 + o) * SEQ + s0 + sc * 8] = w;
  }
}

// ---------------------------------------------------------------------------
// Kernel 3: 2-way split-k causal flash attention, KBLK=64, 1024 blocks.
// Counted-vmcnt pipeline with the aug prefetch accounted in the queue:
//   prologue issues [Q(3), aug(6), G0(4)]; per iter: G_{t+1}(4) then
//   vmcnt(4|10|6) = exactly "current tile's GLDS retired", never draining
//   the in-flight aug/next-tile loads (round-6 bug: vmcnt(4) drained the
//   6 aug loads + 2 new GLDS serially every tile).
// ---------------------------------------------------------------------------
__global__ __launch_bounds__(256, 4) void attn_kernel(
    const us* __restrict__ qs, const float* __restrict__ qt,
    const us* __restrict__ ks, const unsigned int* __restrict__ kta,
    const us* __restrict__ vT, const us* __restrict__ vtc,
    const float* __restrict__ scale_p, float* __restrict__ part)
{
  // XCD-aware swizzle: 32 blocks of one bh land on one XCD.
  const int f = blockIdx.x;
  const int xcd = f & 7, idx = f >> 3;
  const int bh = xcd * 4 + (idx >> 5);
  const int inner = idx & 31;
  const int xb = inner >> 1;
  const int hf = inner & 1;
  const float al2 = (2.0f / scale_p[0]) * 1.44269504088896f;  // a * log2(e)

  __shared__ alignas(16) us lK[2][64 * 64];
  __shared__ alignas(16) us lV[2][64 * 64];
  __shared__ alignas(16) us lP[4][16 * 40];   // 80B rows, 16B-aligned

  const int tid  = threadIdx.x;
  const int lane = tid & 63;
  const int wave = tid >> 6;
  const int arow = lane & 15;
  const int agrp = lane >> 4;

  const size_t bhbase = (size_t)bh * SEQ;
  const us* kgp = ks + bhbase * 64;
  const us* vgp = vT + (size_t)bh * 64 * SEQ;
  const unsigned int* ktp = kta + bhbase;
  const us* vtp = vtc + (size_t)(arow & 1) * NROW + bhbase;

  const int rl   = lane >> 3;
  const int chx  = ((lane & 7) ^ rl) * 8;
  const int r0s  = wave * 8 + rl;
  const int r1s  = r0s + 32;
  const int dsl0 = (agrp ^ (arow & 7)) * 8;
  const int dsl1 = ((4 + agrp) ^ (arow & 7)) * 8;
  us* myP = &lP[wave][0];
  const int pw0 = arow * 40 + agrp * 4;   // b64 write slot (c2=0); +16 for c2=1
  const int prd = arow * 40 + agrp * 8;   // b128 read slot

#define ASTAGE(buf, t64) do { \
    const int kk0 = (t64) * 64; \
    GLDS(kgp + (size_t)(kk0 + r0s) * 64 + chx, &lK[buf][wave * 512]); \
    GLDS(kgp + (size_t)(kk0 + r1s) * 64 + chx, &lK[buf][2048 + wave * 512]); \
    GLDS(vgp + (size_t)r0s * SEQ + kk0 + chx, &lV[buf][wave * 512]); \
    GLDS(vgp + (size_t)r1s * SEQ + kk0 + chx, &lV[buf][2048 + wave * 512]); \
  } while (0)

  short8 ones8, zero8 = {};
#pragma unroll
  for (int j = 0; j < 8; ++j) ones8[j] = (short)0x3F80;

  for (int seg = 0; seg < 2; ++seg) {
    const int qb = seg ? (31 - xb) : xb;
    const int q0 = qb * 64;
    const int c0 = (qb + 2) >> 1;           // ceil((qb+1)/2)
    const int t_lo = hf ? c0 : 0;
    const int t_hi = hf ? (qb + 1) : c0;
    const int nt = t_hi - t_lo;
    const int wq = wave * 16 + arow;

    f32x4 acc[5] = {};

    if (nt > 0) {
      // Q fragments + time terms FIRST (keeps the GLDS queue tail clean)
      const us* qp = qs + (bhbase + q0 + wq) * 64;
      short8 qf0 = *(const short8*)(qp + agrp * 8);
      short8 qf1 = *(const short8*)(qp + 32 + agrp * 8);
      float qtv = qt[bhbase + q0 + wq];
      us qh = f2b(qtv);
      us ql = f2b(qtv - b2f(qh));
      short8 qf2 = {};
      if (agrp == 0) { qf2[0] = (short)qh; qf2[1] = (short)qh; qf2[2] = (short)ql; }

      // aug regs for first tile (kta packed u32 per k-row; vt hi/lo slices)
      unsigned int ka[4];
      short8 va0, va1;
      {
        const int kk0 = t_lo * 64;
#pragma unroll
        for (int c = 0; c < 4; ++c) ka[c] = ktp[kk0 + c * 16 + arow];
        va0 = *(const short8*)(vtp + kk0 + agrp * 8);
        va1 = *(const short8*)(vtp + kk0 + 32 + agrp * 8);
      }
      __builtin_amdgcn_sched_barrier(0);
      ASTAGE(0, t_lo);
      __builtin_amdgcn_sched_barrier(0);

      for (int it = 0; it < nt; ++it) {
        const int t = t_lo + it;
        const int cur = it & 1;
        if (it < nt - 1) {
          ASTAGE(cur ^ 1, t + 1);
          __builtin_amdgcn_sched_barrier(0);
          // queue after current tile's GLDS: aug_t(6) + G_{t+1}(4) = 10;
          // at it==0 the prologue loads sit BEFORE G_0, so 4 suffices.
          if (it == 0) asm volatile("s_waitcnt vmcnt(4)");
          else         asm volatile("s_waitcnt vmcnt(10)");
        } else {
          __builtin_amdgcn_sched_barrier(0);
          if (nt > 1) asm volatile("s_waitcnt vmcnt(6)");   // aug_last in flight
          else        asm volatile("s_waitcnt vmcnt(0)");
        }
        __builtin_amdgcn_sched_barrier(0);
        __builtin_amdgcn_s_barrier();

        const us* Kb = lK[cur];
        const us* Vb = lV[cur];

        // ---- S^T = K' Q'^T (augmented: includes -qt*kt hi/lo) ----
        f32x4 sS[4] = {};
        __builtin_amdgcn_s_setprio(1);
#pragma unroll
        for (int c = 0; c < 4; ++c) {
          short8 kf = *(const short8*)&Kb[(c * 16 + arow) * 64 + dsl0];
          sS[c] = __builtin_amdgcn_mfma_f32_16x16x32_bf16(kf, qf0, sS[c], 0, 0, 0);
        }
#pragma unroll
        for (int c = 0; c < 4; ++c) {
          short8 kf = *(const short8*)&Kb[(c * 16 + arow) * 64 + dsl1];
          sS[c] = __builtin_amdgcn_mfma_f32_16x16x32_bf16(kf, qf1, sS[c], 0, 0, 0);
        }
#pragma unroll
        for (int c = 0; c < 4; ++c) {
          short8 kf2 = {};
          if (agrp == 0) {
            unsigned int w0 = ka[c];
            kf2[0] = (short)(w0 & 0xFFFFu);
            kf2[1] = (short)(w0 >> 16);
            kf2[2] = (short)(w0 & 0xFFFFu);
          }
          sS[c] = __builtin_amdgcn_mfma_f32_16x16x32_bf16(kf2, qf2, sS[c], 0, 0, 0);
        }
        __builtin_amdgcn_s_setprio(0);

        // ---- P = exp2(al2 * logit); causal-mask -> exact 0 ----
#pragma unroll
        for (int c = 0; c < 4; ++c)
#pragma unroll
          for (int r = 0; r < 4; ++r)
            sS[c][r] = exp2f(al2 * sS[c][r]);
        if (t == qb) {
#pragma unroll
          for (int c = 0; c < 4; ++c)
#pragma unroll
            for (int r = 0; r < 4; ++r)
              if (c * 16 + agrp * 4 + r > wq) sS[c][r] = 0.f;
        }

        // ---- PV: 2 phases over kc, wave-private 1KB P tile reused ----
        {
          uint2v w;
          w[0] = pk2(sS[0][0], sS[0][1]); w[1] = pk2(sS[0][2], sS[0][3]);
          *(uint2v*)&myP[pw0] = w;
          w[0] = pk2(sS[1][0], sS[1][1]); w[1] = pk2(sS[1][2], sS[1][3]);
          *(uint2v*)&myP[pw0 + 16] = w;
          short8 pf = *(const short8*)&myP[prd];
          __builtin_amdgcn_s_setprio(1);
#pragma unroll
          for (int dc = 0; dc < 4; ++dc) {
            short8 vf = *(const short8*)&Vb[(dc * 16 + arow) * 64 + dsl0];
            acc[dc] = __builtin_amdgcn_mfma_f32_16x16x32_bf16(pf, vf, acc[dc], 0, 0, 0);
          }
          short8 vf4 = (arow < 2) ? va0 : ((arow == 2) ? ones8 : zero8);
          acc[4] = __builtin_amdgcn_mfma_f32_16x16x32_bf16(pf, vf4, acc[4], 0, 0, 0);
          __builtin_amdgcn_s_setprio(0);
        }
        {
          uint2v w;
          w[0] = pk2(sS[2][0], sS[2][1]); w[1] = pk2(sS[2][2], sS[2][3]);
          *(uint2v*)&myP[pw0] = w;
          w[0] = pk2(sS[3][0], sS[3][1]); w[1] = pk2(sS[3][2], sS[3][3]);
          *(uint2v*)&myP[pw0 + 16] = w;
          short8 pf = *(const short8*)&myP[prd];
          __builtin_amdgcn_s_setprio(1);
#pragma unroll
          for (int dc = 0; dc < 4; ++dc) {
            short8 vf = *(const short8*)&Vb[(dc * 16 + arow) * 64 + dsl1];
            acc[dc] = __builtin_amdgcn_mfma_f32_16x16x32_bf16(pf, vf, acc[dc], 0, 0, 0);
          }
          short8 vf4 = (arow < 2) ? va1 : ((arow == 2) ? ones8 : zero8);
          acc[4] = __builtin_amdgcn_mfma_f32_16x16x32_bf16(pf, vf4, acc[4], 0, 0, 0);
          __builtin_amdgcn_s_setprio(0);
        }

        // aug prefetch for next tile (stays in flight across the barrier;
        // accounted as the 6-deep tail in the next iteration's vmcnt(10))
        if (it + 1 < nt) {
          const int kk0 = (t + 1) * 64;
#pragma unroll
          for (int c = 0; c < 4; ++c) ka[c] = ktp[kk0 + c * 16 + arow];
          va0 = *(const short8*)(vtp + kk0 + agrp * 8);
          va1 = *(const short8*)(vtp + kk0 + 32 + agrp * 8);
        }
        __builtin_amdgcn_sched_barrier(0);
        __builtin_amdgcn_s_barrier();   // reads done: safe to overwrite other buf
      }
    }

    // ---- epilogue: write un-normalized partial (zeros for empty seg) ----
    const size_t pb = ((size_t)(bh * 32 + qb) * 2 + hf) * 64;
#pragma unroll
    for (int r = 0; r < 4; ++r) {
      float t0 = __shfl(acc[4][r], (agrp << 4) | 0);
      float t1 = __shfl(acc[4][r], (agrp << 4) | 1);
      float ls = __shfl(acc[4][r], (agrp << 4) | 2);
      size_t rp = (pb + wave * 16 + agrp * 4 + r) * 68;
#pragma unroll
      for (int dc = 0; dc < 4; ++dc)
        part[rp + dc * 16 + arow] = acc[dc][r];
      if (arow == 0) {
        part[rp + 64] = t0 + t1;
        part[rp + 65] = ls;
        part[rp + 66] = 0.0f;
      }
    }
  }
}

// ---------------------------------------------------------------------------
// Kernel 4: merge split-k partials, mean over heads, Lorentz normalization.
// One wave per (b,s); lane = space dim d. Empty halves have L=0 (exact).
// ---------------------------------------------------------------------------
__global__ __launch_bounds__(256) void finalize_kernel(
    const float* __restrict__ part, const float* __restrict__ scale_p,
    float* __restrict__ out)
{
  const int tid  = threadIdx.x;
  const int lane = tid & 63;
  const int gw = blockIdx.x * 4 + (tid >> 6);
  const int b = gw >> 11, si = gw & (SEQ - 1);
  const int qb = si >> 6, row = si & 63;
  const float al2 = (2.0f / scale_p[0]) * 1.44269504088896f;

  float vsum = 0.f, tsum = 0.f;
#pragma unroll
  for (int h = 0; h < NH; ++h) {
    const size_t tile = (size_t)(b * NH + h) * 32 + qb;
    const size_t b0 = (tile * 2 * 64 + row) * 68;
    const size_t b1 = ((tile * 2 + 1) * 64 + row) * 68;
    float A1 = part[b0 + lane];
    float A2 = part[b1 + lane];
    float T1 = part[b0 + 64], L1 = part[b0 + 65], M1 = part[b0 + 66];
    float T2 = part[b1 + 64], L2 = part[b1 + 65], M2 = part[b1 + 66];
    float ms = fmaxf(M1, M2);
    float f1 = exp2f(al2 * (M1 - ms));
    float f2 = exp2f(al2 * (M2 - ms));
    float inv = 1.0f / (f1 * L1 + f2 * L2);
    vsum = fmaf(fmaf(f1, A1, f2 * A2), inv, vsum);
    tsum = fmaf(fmaf(f1, T1, f2 * T2), inv, tsum);
  }
  float ave  = vsum * 0.125f;
  float tave = tsum * 0.125f;
  float contrib = ave * ave;
  if (lane == 0) contrib -= tave * tave;
  contrib += __shfl_xor(contrib, 1);
  contrib += __shfl_xor(contrib, 2);
  contrib += __shfl_xor(contrib, 4);
  contrib += __shfl_xor(contrib, 8);
  contrib += __shfl_xor(contrib, 16);
  contrib += __shfl_xor(contrib, 32);
  float denom = sqrtf(fmaxf(fabsf(contrib), 1e-8f));
  size_t ob = ((size_t)b * SEQ + si) * (size_t)DD;
  out[ob + 1 + lane] = ave / denom;
  if (lane == 0) out[ob] = tave / denom;
}

// ---------------------------------------------------------------------------
extern "C" void kernel_launch(void* const* d_in, const int* in_sizes, int n_in,
                              void* d_out, int out_size, void* d_ws, size_t ws_size,
                              hipStream_t stream) {
  const float* Xq  = (const float*)d_in[0];
  const float* Xs  = (const float*)d_in[1];
  const float* Wq  = (const float*)d_in[2];
  const float* Bq  = (const float*)d_in[3];
  const float* Wk  = (const float*)d_in[4];
  const float* Bk  = (const float*)d_in[5];
  const float* Wv  = (const float*)d_in[6];
  const float* Bv  = (const float*)d_in[7];
  const float* scale = (const float*)d_in[8];
  float* out = (float*)d_out;

  char* p = (char*)d_ws;

  // Region 0 (35.7 MB): partials, overlapped with bf16 X and W copies
  // (proj consumes Xb/Wb before attn writes part).
  float* part = (float*)p;
  us* Xqb   = (us*)p;
  us* Xsb   = (us*)(p + 16777216);
  us* Wqb16 = (us*)(p + 33554432);
  us* Wkb16 = (us*)(p + 34078720);
  us* Wvb16 = (us*)(p + 34603008);
  p += (size_t)1024 * 2 * 64 * 68 * 4;             // 35,651,584
  us* qsb = (us*)p; p += (size_t)NROW * 64 * 2;
  us* ksb = (us*)p; p += (size_t)NROW * 64 * 2;
  us* vsb = (us*)p; p += (size_t)NROW * 64 * 2;
  us* vTb = (us*)p; p += (size_t)NROW * 64 * 2;
  float* qtb = (float*)p; p += (size_t)NROW * 4;
  unsigned int* ktaw = (unsigned int*)p; p += (size_t)NROW * 4;
  us* vtcw = (us*)p; p += (size_t)NROW * 2 * 2;

  tobf16_kernel<<<dim3(1024, 5), 256, 0, stream>>>(
      Xq, Xs, Wq, Wk, Wv, Xqb, Xsb, Wqb16, Wkb16, Wvb16);
  proj_kernel<<<dim3(1024, 1, 3), 256, 0, stream>>>(
      Xqb, Xsb, Wqb16, Wkb16, Wvb16, Bq, Bk, Bv,
      qsb, qtb, ksb, ktaw, vsb, vtcw);
  transpose_v_kernel<<<dim3(SEQ / 64, BATCH * NH), 256, 0, stream>>>(vsb, vTb);
  attn_kernel<<<dim3(1024), 256, 0, stream>>>(
      qsb, qtb, ksb, ktaw, vTb, vtcw, scale, part);
  finalize_kernel<<<(BATCH * SEQ) / 4, 256, 0, stream>>>(part, scale, out);
}